// Round 12
// baseline (271.498 us; speedup 1.0000x reference)
//
#include <hip/hip_runtime.h>
#include <hip/hip_bf16.h>

// GIN x2 layers x2 branches + per-graph 9x9 gram einsum.
// Round 12: mlp1 -> 512-thread branch-parallel (waves 0-3 = s, 4-7 = t,
// direct z1cat stores; round-10-verified bytes); wpack fused into the
// prep kernel; einsum -> 6 graphs / 512 threads. mlp2 at its measured
// floor. 6 dispatches. All per-accumulator arithmetic sequences and f2bf
// points unchanged -> absmax must stay exactly 14.5.

typedef __attribute__((ext_vector_type(8))) short short8;
typedef __attribute__((ext_vector_type(4))) float f32x4;

#define MAXDEG 64

__device__ inline unsigned short f2bf(float f) {
    union { float f; unsigned u; } v; v.f = f;
    unsigned r = v.u + 0x7fffu + ((v.u >> 16) & 1u);   // RNE
    return (unsigned short)(r >> 16);
}
__device__ inline float bflo(unsigned u) { return __uint_as_float(u << 16); }
__device__ inline float bfhi(unsigned u) { return __uint_as_float(u & 0xffff0000u); }
__device__ inline unsigned packbf(float a, float b) {
    return (unsigned)f2bf(a) | ((unsigned)f2bf(b) << 16);
}

// pack offsets (ushort units): [w1s][w2s][w3s][w4s][w1t][w2t][w3t][w4t]
#define W1S_OFF 0
#define W2S_OFF 4096
#define W3S_OFF 20480
#define W4S_OFF 36864
#define W1T_OFF 45056
#define W2T_OFF 49152
#define W3T_OFF 65536
#define W4T_OFF 81920
#define PACK_USHORTS 90112
#define WPACK_BLOCKS 176

// ---------------- prep: weight packing + x padding + deg zeroing (one kernel)
// Blocks [0,176): pack one 16x32 B-frag tile each (tid<64 active).
// Blocks [176,...): xpad[n*32+f] = f<30 ? x[n*30+f] : 0; deg zeroing.
__global__ __launch_bounds__(256) void prep_kernel(
    const float* w0, const float* w1, const float* w2, const float* w3,
    const float* w4, const float* w5, const float* w6, const float* w7,
    unsigned short* __restrict__ pack,
    const float* __restrict__ x, float* __restrict__ xpad,
    int* __restrict__ deg, int N)
{
    if (blockIdx.x < WPACK_BLOCKS) {
        if (threadIdx.x >= 64) return;
        const int prefix[9] = {0, 8, 40, 72, 88, 96, 128, 160, 176};
        const int KTa[8] = {1, 4, 4, 4, 1, 4, 4, 4};
        const int KRa[8] = {30, 128, 128, 128, 30, 128, 128, 128};
        const int Ca[8]  = {128, 128, 128, 64, 128, 128, 128, 64};
        const int DOFF[8] = {W1S_OFF, W2S_OFF, W3S_OFF, W4S_OFF,
                             W1T_OFF, W2T_OFF, W3T_OFF, W4T_OFF};
        const float* Ws[8] = {w0, w1, w2, w3, w4, w5, w6, w7};
        int bid = blockIdx.x;
        int mi = 0;
        while (mi < 7 && bid >= prefix[mi + 1]) ++mi;
        int lt = bid - prefix[mi];
        int kt = lt % KTa[mi], ct = lt / KTa[mi];
        const float* W = Ws[mi];
        int l = threadIdx.x;
        int n = ct * 16 + (l & 15);
        for (int j = 0; j < 8; ++j) {
            int k = kt * 32 + (l >> 4) * 8 + j;
            float v = (k < KRa[mi]) ? W[(size_t)k * Ca[mi] + n] : 0.f;
            pack[(size_t)DOFF[mi] + (size_t)lt * 512 + l * 8 + j] = f2bf(v);
        }
    } else {
        int gid = (blockIdx.x - WPACK_BLOCKS) * 256 + threadIdx.x;
        if (gid < N) deg[gid] = 0;
        if (gid >= N * 32) return;
        int n = gid >> 5, f = gid & 31;
        xpad[gid] = (f < 30) ? x[(size_t)n * 30 + f] : 0.f;
    }
}

// ------------------------- adjacency build: single-pass bucket scatter
__global__ __launch_bounds__(256) void bucket_kernel(
    const int* __restrict__ src, const int* __restrict__ dst,
    int* __restrict__ deg, int* __restrict__ colb, int E)
{
    int e = blockIdx.x * 256 + threadIdx.x;
    if (e < E) {
        int d = dst[e];
        int slot = atomicAdd(&deg[d], 1);
        if (slot < MAXDEG) colb[(size_t)d * MAXDEG + slot] = src[e];
    }
}

// ------------------------------------------- layer-1 aggregation (gather)
// 8 lanes/node, float4 (16B) per lane over xpad[N,32] fp32.
__global__ __launch_bounds__(256) void gather30_kernel(
    const float* __restrict__ xpad, const int* __restrict__ deg,
    const int* __restrict__ colb, unsigned short* __restrict__ h1, int N)
{
    int gid = blockIdx.x * 256 + threadIdx.x;
    int node = gid >> 3;
    if (node >= N) return;
    int l = gid & 7;
    const float4* base = (const float4*)xpad;   // 8 float4 per row
    float4 a = base[(size_t)node * 8 + l];      // self (exact fp32)
    const int* col = colb + (size_t)node * MAXDEG;
    int e = min(deg[node], MAXDEG);
    int i = 0;
    for (; i + 4 <= e; i += 4) {
        int s0 = col[i], s1 = col[i + 1], s2 = col[i + 2], s3 = col[i + 3];
        float4 v0 = base[(size_t)s0 * 8 + l];
        float4 v1 = base[(size_t)s1 * 8 + l];
        float4 v2 = base[(size_t)s2 * 8 + l];
        float4 v3 = base[(size_t)s3 * 8 + l];
        a.x += v0.x; a.y += v0.y; a.z += v0.z; a.w += v0.w;
        a.x += v1.x; a.y += v1.y; a.z += v1.z; a.w += v1.w;
        a.x += v2.x; a.y += v2.y; a.z += v2.z; a.w += v2.w;
        a.x += v3.x; a.y += v3.y; a.z += v3.z; a.w += v3.w;
    }
    for (; i + 2 <= e; i += 2) {
        int s0 = col[i], s1 = col[i + 1];
        float4 v0 = base[(size_t)s0 * 8 + l];
        float4 v1 = base[(size_t)s1 * 8 + l];
        a.x += v0.x; a.y += v0.y; a.z += v0.z; a.w += v0.w;
        a.x += v1.x; a.y += v1.y; a.z += v1.z; a.w += v1.w;
    }
    for (; i < e; ++i) {
        float4 v0 = base[(size_t)col[i] * 8 + l];
        a.x += v0.x; a.y += v0.y; a.z += v0.z; a.w += v0.w;
    }
    uint2 o; o.x = packbf(a.x, a.y); o.y = packbf(a.z, a.w);
    ((uint2*)h1)[(size_t)node * 8 + l] = o;
}

// ------------- layer-1 MLP: 512 threads, branch-parallel (waves 0-3 = s,
// waves 4-7 = t, per-branch hm), direct z1cat stores. Bytes identical to
// round 10's verified MLP phase.
__global__ __launch_bounds__(512, 8) void mlp1_kernel(
    const unsigned short* __restrict__ h1, const unsigned short* __restrict__ pack,
    const float* __restrict__ b1s, const float* __restrict__ b2s,
    const float* __restrict__ b1t, const float* __restrict__ b2t,
    unsigned short* __restrict__ z1cat, int N)
{
    __shared__ __align__(16) unsigned short hs[64 * 40];        //  5.1 KB
    __shared__ __align__(16) unsigned short hm[2][64 * 136];    // 34.8 KB
    const int tid = threadIdx.x;
    const int n0blk = blockIdx.x * 64;

    // ---- stage h1 rows (32 bf16 each): 512 thr x uint2 covers 64x32 ----
    {
        int row = tid >> 3, off = tid & 7;
        int gn = n0blk + row;
        uint2 v = {0u, 0u};
        if (gn < N) v = *(const uint2*)&h1[(size_t)gn * 32 + off * 4];
        *(uint2*)&hs[row * 40 + off * 4] = v;
    }
    __syncthreads();

    const int half = tid >> 8;         // 0 = branch s, 1 = branch t
    const int ltid = tid & 255;
    const int wv = ltid >> 6, l = ltid & 63, q = l >> 4, m = l & 15;
    const float* B1 = half ? b1t : b1s;
    const float* B2 = half ? b2t : b2s;
    const int w1off = half ? W1T_OFF : W1S_OFF;
    const int w2off = half ? W2T_OFF : W2S_OFF;
    unsigned short* hmb = hm[half];

    // ---- stage 1: hm = relu(h1 @ W1 + b1), K=32 single MFMA ----
    {
        short8 a[4];
        #pragma unroll
        for (int nt = 0; nt < 4; ++nt)
            a[nt] = *(const short8*)&hs[(nt * 16 + m) * 40 + q * 8];
        #pragma unroll
        for (int ci = 0; ci < 2; ++ci) {
            int ct = wv * 2 + ci;
            short8 bf = *(const short8*)&pack[w1off + ((size_t)ct * 64 + l) * 8];
            float bias = B1[ct * 16 + m];
            #pragma unroll
            for (int nt = 0; nt < 4; ++nt) {
                f32x4 acc = {0.f, 0.f, 0.f, 0.f};
                acc = __builtin_amdgcn_mfma_f32_16x16x32_bf16(a[nt], bf, acc, 0, 0, 0);
                #pragma unroll
                for (int r = 0; r < 4; ++r) {
                    float v = fmaxf(acc[r] + bias, 0.f);
                    hmb[(nt * 16 + q * 4 + r) * 136 + ct * 16 + m] = f2bf(v);
                }
            }
        }
    }
    __syncthreads();

    // ---- stage 2: z1cat slice = hm @ W2 + b2 (K=128), direct store ----
    for (int nt = 0; nt < 4; ++nt) {
        short8 a[4];
        #pragma unroll
        for (int kt = 0; kt < 4; ++kt)
            a[kt] = *(const short8*)&hmb[(nt * 16 + m) * 136 + kt * 32 + q * 8];
        #pragma unroll
        for (int ci = 0; ci < 2; ++ci) {
            int ct = wv * 2 + ci;
            f32x4 acc = {0.f, 0.f, 0.f, 0.f};
            #pragma unroll
            for (int kt = 0; kt < 4; ++kt) {
                short8 bf = *(const short8*)&pack[w2off + ((size_t)(ct * 4 + kt) * 64 + l) * 8];
                acc = __builtin_amdgcn_mfma_f32_16x16x32_bf16(a[kt], bf, acc, 0, 0, 0);
            }
            float bias = B2[ct * 16 + m];
            #pragma unroll
            for (int r = 0; r < 4; ++r) {
                int gn = n0blk + nt * 16 + q * 4 + r;
                if (gn < N)
                    z1cat[(size_t)gn * 256 + half * 128 + ct * 16 + m] =
                        f2bf(acc[r] + bias);
            }
        }
    }
}

// ---------------- layer-2: gather + both-branch MLP fused (512 thr, 32 nodes)
// At its measured floor (~75 us across 4 structural variants).
__global__ __launch_bounds__(512, 8) void mlp2_kernel(
    const unsigned short* __restrict__ z1, const int* __restrict__ deg,
    const int* __restrict__ colb, const unsigned short* __restrict__ pack,
    const float* __restrict__ b3s, const float* __restrict__ b4s,
    const float* __restrict__ b3t, const float* __restrict__ b4t,
    float* __restrict__ z2cat, int N)
{
    __shared__ __align__(16) unsigned short hs[32 * 264];
    __shared__ __align__(16) unsigned short hm[32 * 136];
    const int tid = threadIdx.x;
    const int n0blk = blockIdx.x * 32;

    // ---- gather-stage: 16 groups x 32 lanes, 2 rows per group ----
    {
        const int g = tid >> 5, l = tid & 31;
        const uint4* base = (const uint4*)z1;        // 32 uint4 per row
        for (int it = 0; it < 2; ++it) {
            int row = it * 16 + g;
            int gn = n0blk + row;
            float a0 = 0.f, a1 = 0.f, a2 = 0.f, a3 = 0.f;
            float a4 = 0.f, a5 = 0.f, a6 = 0.f, a7 = 0.f;
            if (gn < N) {
                uint4 s = base[(size_t)gn * 32 + l];     // self
                a0 = bflo(s.x); a1 = bfhi(s.x); a2 = bflo(s.y); a3 = bfhi(s.y);
                a4 = bflo(s.z); a5 = bfhi(s.z); a6 = bflo(s.w); a7 = bfhi(s.w);
                const int* col = colb + (size_t)gn * MAXDEG;
                int e = min(deg[gn], MAXDEG);
                int i = 0;
                for (; i + 4 <= e; i += 4) {
                    int s0 = col[i], s1 = col[i + 1], s2 = col[i + 2], s3 = col[i + 3];
                    uint4 v0 = base[(size_t)s0 * 32 + l];
                    uint4 v1 = base[(size_t)s1 * 32 + l];
                    uint4 v2 = base[(size_t)s2 * 32 + l];
                    uint4 v3 = base[(size_t)s3 * 32 + l];
                    a0 += bflo(v0.x); a1 += bfhi(v0.x); a2 += bflo(v0.y); a3 += bfhi(v0.y);
                    a4 += bflo(v0.z); a5 += bfhi(v0.z); a6 += bflo(v0.w); a7 += bfhi(v0.w);
                    a0 += bflo(v1.x); a1 += bfhi(v1.x); a2 += bflo(v1.y); a3 += bfhi(v1.y);
                    a4 += bflo(v1.z); a5 += bfhi(v1.z); a6 += bflo(v1.w); a7 += bfhi(v1.w);
                    a0 += bflo(v2.x); a1 += bfhi(v2.x); a2 += bflo(v2.y); a3 += bfhi(v2.y);
                    a4 += bflo(v2.z); a5 += bfhi(v2.z); a6 += bflo(v2.w); a7 += bfhi(v2.w);
                    a0 += bflo(v3.x); a1 += bfhi(v3.x); a2 += bflo(v3.y); a3 += bfhi(v3.y);
                    a4 += bflo(v3.z); a5 += bfhi(v3.z); a6 += bflo(v3.w); a7 += bfhi(v3.w);
                }
                for (; i + 2 <= e; i += 2) {
                    int s0 = col[i], s1 = col[i + 1];
                    uint4 v0 = base[(size_t)s0 * 32 + l];
                    uint4 v1 = base[(size_t)s1 * 32 + l];
                    a0 += bflo(v0.x); a1 += bfhi(v0.x); a2 += bflo(v0.y); a3 += bfhi(v0.y);
                    a4 += bflo(v0.z); a5 += bfhi(v0.z); a6 += bflo(v0.w); a7 += bfhi(v0.w);
                    a0 += bflo(v1.x); a1 += bfhi(v1.x); a2 += bflo(v1.y); a3 += bfhi(v1.y);
                    a4 += bflo(v1.z); a5 += bfhi(v1.z); a6 += bflo(v1.w); a7 += bfhi(v1.w);
                }
                for (; i < e; ++i) {
                    uint4 v0 = base[(size_t)col[i] * 32 + l];
                    a0 += bflo(v0.x); a1 += bfhi(v0.x); a2 += bflo(v0.y); a3 += bfhi(v0.y);
                    a4 += bflo(v0.z); a5 += bfhi(v0.z); a6 += bflo(v0.w); a7 += bfhi(v0.w);
                }
            }
            short8 st;
            st[0] = (short)f2bf(a0); st[1] = (short)f2bf(a1);
            st[2] = (short)f2bf(a2); st[3] = (short)f2bf(a3);
            st[4] = (short)f2bf(a4); st[5] = (short)f2bf(a5);
            st[6] = (short)f2bf(a6); st[7] = (short)f2bf(a7);
            *(short8*)&hs[row * 264 + l * 8] = st;
        }
    }
    __syncthreads();

    const int wv = tid >> 6, l = tid & 63, q = l >> 4, m = l & 15;

    for (int br = 0; br < 2; ++br) {
        const int w1off = br ? W3T_OFF : W3S_OFF;
        const int w2off = br ? W4T_OFF : W4S_OFF;
        const float* B1 = br ? b3t : b3s;
        const float* B2 = br ? b4t : b4s;
        if (br) __syncthreads();   // br0 stage2 hm reads done before rewrite

        // ---- stage 1: hm = relu(hs[:, br*128..] @ W3 + b3), K=128 ----
        #pragma unroll
        for (int ti = 0; ti < 2; ++ti) {
            const int tile = wv * 2 + ti;
            const int ct = tile & 7;
            const int nt = tile >> 3;
            float bias = B1[ct * 16 + m];
            short8 a[4];
            #pragma unroll
            for (int kt = 0; kt < 4; ++kt)
                a[kt] = *(const short8*)&hs[(nt * 16 + m) * 264 + br * 128 + kt * 32 + q * 8];
            f32x4 acc = {0.f, 0.f, 0.f, 0.f};
            #pragma unroll
            for (int kt = 0; kt < 4; ++kt) {
                short8 bf = *(const short8*)&pack[w1off + ((size_t)(ct * 4 + kt) * 64 + l) * 8];
                acc = __builtin_amdgcn_mfma_f32_16x16x32_bf16(a[kt], bf, acc, 0, 0, 0);
            }
            #pragma unroll
            for (int r = 0; r < 4; ++r) {
                float v = fmaxf(acc[r] + bias, 0.f);
                hm[(nt * 16 + q * 4 + r) * 136 + ct * 16 + m] = f2bf(v);
            }
        }
        __syncthreads();

        // ---- stage 2: z2cat slice = hm @ W4 + b4 (8 tiles over 8 waves) ----
        {
            const int ct = wv & 3;
            const int nt = wv >> 2;
            float bias = B2[ct * 16 + m];
            short8 a[4];
            #pragma unroll
            for (int kt = 0; kt < 4; ++kt)
                a[kt] = *(const short8*)&hm[(nt * 16 + m) * 136 + kt * 32 + q * 8];
            f32x4 acc = {0.f, 0.f, 0.f, 0.f};
            #pragma unroll
            for (int kt = 0; kt < 4; ++kt) {
                short8 bf = *(const short8*)&pack[w2off + ((size_t)(ct * 4 + kt) * 64 + l) * 8];
                acc = __builtin_amdgcn_mfma_f32_16x16x32_bf16(a[kt], bf, acc, 0, 0, 0);
            }
            #pragma unroll
            for (int r = 0; r < 4; ++r) {
                int gn = n0blk + nt * 16 + q * 4 + r;
                if (gn < N)
                    z2cat[(size_t)gn * 128 + br * 64 + ct * 16 + m] = acc[r] + bias;
            }
        }
    }
}

// ---------------- per-graph 9x9 gram from z2cat [N,128] (s=0..63,t=64..127)
// 6 graphs per 512-thread block; 486 compute lanes; k-order unchanged.
__global__ __launch_bounds__(512) void einsum9_kernel(
    const float* __restrict__ z2cat, float* __restrict__ out, int G)
{
    int g0 = blockIdx.x * 6;
    __shared__ float ss[54][68];
    __shared__ float tt[54][68];
    const int tid = threadIdx.x;
    for (int idx = tid; idx < 54 * 16; idx += 512) {
        int n = idx >> 4, k4 = idx & 15;
        int g = g0 + n / 9;
        if (g < G) {
            size_t row = (size_t)(g * 9 + (n % 9)) * 128;
            float4 a = *(const float4*)&z2cat[row + k4 * 4];
            float4 b = *(const float4*)&z2cat[row + 64 + k4 * 4];
            *(float4*)&ss[n][k4 * 4] = a;
            *(float4*)&tt[n][k4 * 4] = b;
        }
    }
    __syncthreads();
    if (tid < 486) {
        int gl = tid / 81, rem = tid - gl * 81;
        int i = rem / 9, j = rem - i * 9;
        int g = g0 + gl;
        if (g < G) {
            float acc = 0.f;
            #pragma unroll
            for (int k = 0; k < 64; ++k) acc += ss[gl * 9 + i][k] * tt[gl * 9 + j][k];
            out[(size_t)g * 81 + i * 9 + j] = acc;
        }
    }
}

extern "C" void kernel_launch(void* const* d_in, const int* in_sizes, int n_in,
                              void* d_out, int out_size, void* d_ws, size_t ws_size,
                              hipStream_t stream)
{
    const float* x  = (const float*)d_in[0];
    const int*   ei = (const int*)d_in[1];
    const int N_ = in_sizes[0] / 30;
    const int E_ = in_sizes[1] / 2;
    const int* src = ei;
    const int* dst = ei + E_;

    const float* w1s = (const float*)d_in[2];
    const float* b1s = (const float*)d_in[3];
    const float* w2s = (const float*)d_in[4];
    const float* b2s = (const float*)d_in[5];
    const float* w3s = (const float*)d_in[6];
    const float* b3s = (const float*)d_in[7];
    const float* w4s = (const float*)d_in[8];
    const float* b4s = (const float*)d_in[9];
    const float* w1t = (const float*)d_in[10];
    const float* b1t = (const float*)d_in[11];
    const float* w2t = (const float*)d_in[12];
    const float* b2t = (const float*)d_in[13];
    const float* w3t = (const float*)d_in[14];
    const float* b3t = (const float*)d_in[15];
    const float* w4t = (const float*)d_in[16];
    const float* b4t = (const float*)d_in[17];

    // ---- workspace layout ----
    int* deg  = (int*)d_ws;                               // N
    int* colb = deg + N_;                                 // N * MAXDEG
    size_t int_bytes = ((size_t)N_ * (1 + MAXDEG)) * sizeof(int);
    size_t pb = (int_bytes + 15) & ~(size_t)15;
    unsigned short* packu = (unsigned short*)((char*)d_ws + pb);
    float* xpad = (float*)(packu + PACK_USHORTS);         // [N,32] fp32
    unsigned short* h1    = (unsigned short*)(xpad + (size_t)N_ * 32); // [N,32] bf16
    unsigned short* z1cat = h1 + (size_t)N_ * 32;         // [N,256] bf16 s||t
    float* z2cat = (float*)(z1cat + (size_t)N_ * 256);    // [N,128] fp32 s||t
    size_t need = pb + (size_t)PACK_USHORTS * 2
                + (size_t)N_ * 32 * 4            // xpad
                + (size_t)N_ * 32 * 2            // h1
                + (size_t)N_ * 256 * 2           // z1cat
                + (size_t)N_ * 128 * 4;          // z2cat
    if (ws_size < need) return;

    const int nbE  = (E_ + 255) / 256;
    const int nb64 = (N_ + 63) / 64;
    const int nb32 = (N_ + 31) / 32;

    // ---- prep: weight packing + x padding + deg zeroing (one kernel) ----
    prep_kernel<<<WPACK_BLOCKS + (N_ * 32 + 255) / 256, 256, 0, stream>>>(
        w1s, w2s, w3s, w4s, w1t, w2t, w3t, w4t, packu, x, xpad, deg, N_);

    // ---- adjacency: single-pass bucket scatter ----
    bucket_kernel<<<nbE, 256, 0, stream>>>(src, dst, deg, colb, E_);

    // ---- layer-1 aggregation: 8 lanes/node float4 gather -> bf16 h1 ----
    gather30_kernel<<<(N_ * 8 + 255) / 256, 256, 0, stream>>>(
        xpad, deg, colb, h1, N_);

    // ---- layer 1: both branches in parallel (MFMA, 512 thr / 64 nodes) ----
    mlp1_kernel<<<nb64, 512, 0, stream>>>(h1, packu,
        b1s, b2s, b1t, b2t, z1cat, N_);

    // ---- layer 2: gather + both branches fused (MFMA, 512 thr / 32 nodes) ----
    mlp2_kernel<<<nb32, 512, 0, stream>>>(z1cat, deg, colb, packu,
        b3s, b4s, b3t, b4t, z2cat, N_);

    // ---- per-graph 9x9 gram: 6 graphs per block ----
    {
        int G = N_ / 9;
        einsum9_kernel<<<(G + 5) / 6, 512, 0, stream>>>(z2cat, (float*)d_out, G);
    }
}

// Round 13
// 244.246 us; speedup vs baseline: 1.1116x; 1.1116x over previous
//
#include <hip/hip_runtime.h>
#include <hip/hip_bf16.h>

// GIN x2 layers x2 branches + per-graph 9x9 gram einsum.
// Round 13: revert to the verified round-11 structure (247.0 us) for mlp1
// (256 thr, serial branches, coalesced LDS-transpose copy-out -- the 2-byte
// direct stores of round 12 were the regression), einsum (3 graphs/256).
// Keep only the prep fusion (wpack + xpad + deg zero in one dispatch).
// 6 dispatches. absmax must stay exactly 14.5.

typedef __attribute__((ext_vector_type(8))) short short8;
typedef __attribute__((ext_vector_type(4))) float f32x4;

#define MAXDEG 64

__device__ inline unsigned short f2bf(float f) {
    union { float f; unsigned u; } v; v.f = f;
    unsigned r = v.u + 0x7fffu + ((v.u >> 16) & 1u);   // RNE
    return (unsigned short)(r >> 16);
}
__device__ inline float bflo(unsigned u) { return __uint_as_float(u << 16); }
__device__ inline float bfhi(unsigned u) { return __uint_as_float(u & 0xffff0000u); }
__device__ inline unsigned packbf(float a, float b) {
    return (unsigned)f2bf(a) | ((unsigned)f2bf(b) << 16);
}

// pack offsets (ushort units): [w1s][w2s][w3s][w4s][w1t][w2t][w3t][w4t]
#define W1S_OFF 0
#define W2S_OFF 4096
#define W3S_OFF 20480
#define W4S_OFF 36864
#define W1T_OFF 45056
#define W2T_OFF 49152
#define W3T_OFF 65536
#define W4T_OFF 81920
#define PACK_USHORTS 90112
#define WPACK_BLOCKS 176

// ---------------- prep: weight packing + x padding + deg zeroing (one kernel)
__global__ __launch_bounds__(256) void prep_kernel(
    const float* w0, const float* w1, const float* w2, const float* w3,
    const float* w4, const float* w5, const float* w6, const float* w7,
    unsigned short* __restrict__ pack,
    const float* __restrict__ x, float* __restrict__ xpad,
    int* __restrict__ deg, int N)
{
    if (blockIdx.x < WPACK_BLOCKS) {
        if (threadIdx.x >= 64) return;
        const int prefix[9] = {0, 8, 40, 72, 88, 96, 128, 160, 176};
        const int KTa[8] = {1, 4, 4, 4, 1, 4, 4, 4};
        const int KRa[8] = {30, 128, 128, 128, 30, 128, 128, 128};
        const int Ca[8]  = {128, 128, 128, 64, 128, 128, 128, 64};
        const int DOFF[8] = {W1S_OFF, W2S_OFF, W3S_OFF, W4S_OFF,
                             W1T_OFF, W2T_OFF, W3T_OFF, W4T_OFF};
        const float* Ws[8] = {w0, w1, w2, w3, w4, w5, w6, w7};
        int bid = blockIdx.x;
        int mi = 0;
        while (mi < 7 && bid >= prefix[mi + 1]) ++mi;
        int lt = bid - prefix[mi];
        int kt = lt % KTa[mi], ct = lt / KTa[mi];
        const float* W = Ws[mi];
        int l = threadIdx.x;
        int n = ct * 16 + (l & 15);
        for (int j = 0; j < 8; ++j) {
            int k = kt * 32 + (l >> 4) * 8 + j;
            float v = (k < KRa[mi]) ? W[(size_t)k * Ca[mi] + n] : 0.f;
            pack[(size_t)DOFF[mi] + (size_t)lt * 512 + l * 8 + j] = f2bf(v);
        }
    } else {
        int gid = (blockIdx.x - WPACK_BLOCKS) * 256 + threadIdx.x;
        if (gid < N) deg[gid] = 0;
        if (gid >= N * 32) return;
        int n = gid >> 5, f = gid & 31;
        xpad[gid] = (f < 30) ? x[(size_t)n * 30 + f] : 0.f;
    }
}

// ------------------------- adjacency build: single-pass bucket scatter
__global__ __launch_bounds__(256) void bucket_kernel(
    const int* __restrict__ src, const int* __restrict__ dst,
    int* __restrict__ deg, int* __restrict__ colb, int E)
{
    int e = blockIdx.x * 256 + threadIdx.x;
    if (e < E) {
        int d = dst[e];
        int slot = atomicAdd(&deg[d], 1);
        if (slot < MAXDEG) colb[(size_t)d * MAXDEG + slot] = src[e];
    }
}

// ------------------------------------------- layer-1 aggregation (gather)
// 8 lanes/node, float4 (16B) per lane over xpad[N,32] fp32.
__global__ __launch_bounds__(256) void gather30_kernel(
    const float* __restrict__ xpad, const int* __restrict__ deg,
    const int* __restrict__ colb, unsigned short* __restrict__ h1, int N)
{
    int gid = blockIdx.x * 256 + threadIdx.x;
    int node = gid >> 3;
    if (node >= N) return;
    int l = gid & 7;
    const float4* base = (const float4*)xpad;   // 8 float4 per row
    float4 a = base[(size_t)node * 8 + l];      // self (exact fp32)
    const int* col = colb + (size_t)node * MAXDEG;
    int e = min(deg[node], MAXDEG);
    int i = 0;
    for (; i + 4 <= e; i += 4) {
        int s0 = col[i], s1 = col[i + 1], s2 = col[i + 2], s3 = col[i + 3];
        float4 v0 = base[(size_t)s0 * 8 + l];
        float4 v1 = base[(size_t)s1 * 8 + l];
        float4 v2 = base[(size_t)s2 * 8 + l];
        float4 v3 = base[(size_t)s3 * 8 + l];
        a.x += v0.x; a.y += v0.y; a.z += v0.z; a.w += v0.w;
        a.x += v1.x; a.y += v1.y; a.z += v1.z; a.w += v1.w;
        a.x += v2.x; a.y += v2.y; a.z += v2.z; a.w += v2.w;
        a.x += v3.x; a.y += v3.y; a.z += v3.z; a.w += v3.w;
    }
    for (; i + 2 <= e; i += 2) {
        int s0 = col[i], s1 = col[i + 1];
        float4 v0 = base[(size_t)s0 * 8 + l];
        float4 v1 = base[(size_t)s1 * 8 + l];
        a.x += v0.x; a.y += v0.y; a.z += v0.z; a.w += v0.w;
        a.x += v1.x; a.y += v1.y; a.z += v1.z; a.w += v1.w;
    }
    for (; i < e; ++i) {
        float4 v0 = base[(size_t)col[i] * 8 + l];
        a.x += v0.x; a.y += v0.y; a.z += v0.z; a.w += v0.w;
    }
    uint2 o; o.x = packbf(a.x, a.y); o.y = packbf(a.z, a.w);
    ((uint2*)h1)[(size_t)node * 8 + l] = o;
}

// ------------------------------------------------- layer-1 MLP (dual branch)
// Round-11 verified: 256 threads, serial branches, coalesced LDS copy-out.
__global__ __launch_bounds__(256) void mlp1_kernel(
    const unsigned short* __restrict__ h1, const unsigned short* __restrict__ pack,
    const float* __restrict__ b1s, const float* __restrict__ b2s,
    const float* __restrict__ b1t, const float* __restrict__ b2t,
    unsigned short* __restrict__ z1cat, int N)
{
    __shared__ __align__(16) unsigned short hs[64 * 40];
    __shared__ __align__(16) unsigned short hm[64 * 136];
    const int tid = threadIdx.x;
    const int n0blk = blockIdx.x * 64;

    // ---- stage h1 rows (32 bf16 each), coalesced 16B/thread ----
    {
        int row = tid >> 2, off = tid & 3;
        int gn = n0blk + row;
        short8 v = {0, 0, 0, 0, 0, 0, 0, 0};
        if (gn < N) v = *(const short8*)&h1[(size_t)gn * 32 + off * 8];
        *(short8*)&hs[row * 40 + off * 8] = v;
    }
    __syncthreads();

    const int wv = tid >> 6, l = tid & 63, q = l >> 4, m = l & 15;

    for (int br = 0; br < 2; ++br) {
        const float* B1 = br ? b1t : b1s;
        const float* B2 = br ? b2t : b2s;
        const int w1off = br ? W1T_OFF : W1S_OFF;
        const int w2off = br ? W2T_OFF : W2S_OFF;

        // ---- stage 1: hm = relu(h1 @ W1 + b1), K=32 single MFMA ----
        {
            short8 a[4];
            #pragma unroll
            for (int nt = 0; nt < 4; ++nt)
                a[nt] = *(const short8*)&hs[(nt * 16 + m) * 40 + q * 8];
            #pragma unroll
            for (int ci = 0; ci < 2; ++ci) {
                int ct = wv * 2 + ci;
                short8 bf = *(const short8*)&pack[w1off + ((size_t)ct * 64 + l) * 8];
                float bias = B1[ct * 16 + m];
                #pragma unroll
                for (int nt = 0; nt < 4; ++nt) {
                    f32x4 acc = {0.f, 0.f, 0.f, 0.f};
                    acc = __builtin_amdgcn_mfma_f32_16x16x32_bf16(a[nt], bf, acc, 0, 0, 0);
                    #pragma unroll
                    for (int r = 0; r < 4; ++r) {
                        float v = fmaxf(acc[r] + bias, 0.f);
                        hm[(nt * 16 + q * 4 + r) * 136 + ct * 16 + m] = f2bf(v);
                    }
                }
            }
        }
        __syncthreads();

        // ---- stage 2: z1 = hm @ W2 + b2 (K=128), defer writeback ----
        f32x4 acc2[4][2];
        #pragma unroll
        for (int nt = 0; nt < 4; ++nt)
            #pragma unroll
            for (int ci = 0; ci < 2; ++ci)
                acc2[nt][ci] = (f32x4){0.f, 0.f, 0.f, 0.f};
        for (int nt = 0; nt < 4; ++nt) {
            short8 a[4];
            #pragma unroll
            for (int kt = 0; kt < 4; ++kt)
                a[kt] = *(const short8*)&hm[(nt * 16 + m) * 136 + kt * 32 + q * 8];
            #pragma unroll
            for (int ci = 0; ci < 2; ++ci) {
                int ct = wv * 2 + ci;
                #pragma unroll
                for (int kt = 0; kt < 4; ++kt) {
                    short8 bf = *(const short8*)&pack[w2off + ((size_t)(ct * 4 + kt) * 64 + l) * 8];
                    acc2[nt][ci] = __builtin_amdgcn_mfma_f32_16x16x32_bf16(a[kt], bf, acc2[nt][ci], 0, 0, 0);
                }
            }
        }
        __syncthreads();   // all hm A-frag reads complete
        #pragma unroll
        for (int ci = 0; ci < 2; ++ci) {
            int ct = wv * 2 + ci;
            float bias = B2[ct * 16 + m];
            #pragma unroll
            for (int nt = 0; nt < 4; ++nt)
                #pragma unroll
                for (int r = 0; r < 4; ++r)
                    hm[(nt * 16 + q * 4 + r) * 136 + ct * 16 + m] =
                        f2bf(acc2[nt][ci][r] + bias);
        }
        __syncthreads();
        // coalesced copy-out: 64 rows x 128 bf16
        for (int c = tid; c < 1024; c += 256) {
            int row = c >> 4, off = c & 15;
            int gn = n0blk + row;
            if (gn < N) {
                short8 v = *(const short8*)&hm[row * 136 + off * 8];
                *(short8*)&z1cat[(size_t)gn * 256 + br * 128 + off * 8] = v;
            }
        }
        __syncthreads();   // before branch t rewrites hm
    }
}

// ---------------- layer-2: gather + both-branch MLP fused (512 thr, 32 nodes)
// At its measured floor (~75 us across 4 structural variants).
__global__ __launch_bounds__(512, 8) void mlp2_kernel(
    const unsigned short* __restrict__ z1, const int* __restrict__ deg,
    const int* __restrict__ colb, const unsigned short* __restrict__ pack,
    const float* __restrict__ b3s, const float* __restrict__ b4s,
    const float* __restrict__ b3t, const float* __restrict__ b4t,
    float* __restrict__ z2cat, int N)
{
    __shared__ __align__(16) unsigned short hs[32 * 264];
    __shared__ __align__(16) unsigned short hm[32 * 136];
    const int tid = threadIdx.x;
    const int n0blk = blockIdx.x * 32;

    // ---- gather-stage: 16 groups x 32 lanes, 2 rows per group ----
    {
        const int g = tid >> 5, l = tid & 31;
        const uint4* base = (const uint4*)z1;        // 32 uint4 per row
        for (int it = 0; it < 2; ++it) {
            int row = it * 16 + g;
            int gn = n0blk + row;
            float a0 = 0.f, a1 = 0.f, a2 = 0.f, a3 = 0.f;
            float a4 = 0.f, a5 = 0.f, a6 = 0.f, a7 = 0.f;
            if (gn < N) {
                uint4 s = base[(size_t)gn * 32 + l];     // self
                a0 = bflo(s.x); a1 = bfhi(s.x); a2 = bflo(s.y); a3 = bfhi(s.y);
                a4 = bflo(s.z); a5 = bfhi(s.z); a6 = bflo(s.w); a7 = bfhi(s.w);
                const int* col = colb + (size_t)gn * MAXDEG;
                int e = min(deg[gn], MAXDEG);
                int i = 0;
                for (; i + 4 <= e; i += 4) {
                    int s0 = col[i], s1 = col[i + 1], s2 = col[i + 2], s3 = col[i + 3];
                    uint4 v0 = base[(size_t)s0 * 32 + l];
                    uint4 v1 = base[(size_t)s1 * 32 + l];
                    uint4 v2 = base[(size_t)s2 * 32 + l];
                    uint4 v3 = base[(size_t)s3 * 32 + l];
                    a0 += bflo(v0.x); a1 += bfhi(v0.x); a2 += bflo(v0.y); a3 += bfhi(v0.y);
                    a4 += bflo(v0.z); a5 += bfhi(v0.z); a6 += bflo(v0.w); a7 += bfhi(v0.w);
                    a0 += bflo(v1.x); a1 += bfhi(v1.x); a2 += bflo(v1.y); a3 += bfhi(v1.y);
                    a4 += bflo(v1.z); a5 += bfhi(v1.z); a6 += bflo(v1.w); a7 += bfhi(v1.w);
                    a0 += bflo(v2.x); a1 += bfhi(v2.x); a2 += bflo(v2.y); a3 += bfhi(v2.y);
                    a4 += bflo(v2.z); a5 += bfhi(v2.z); a6 += bflo(v2.w); a7 += bfhi(v2.w);
                    a0 += bflo(v3.x); a1 += bfhi(v3.x); a2 += bflo(v3.y); a3 += bfhi(v3.y);
                    a4 += bflo(v3.z); a5 += bfhi(v3.z); a6 += bflo(v3.w); a7 += bfhi(v3.w);
                }
                for (; i + 2 <= e; i += 2) {
                    int s0 = col[i], s1 = col[i + 1];
                    uint4 v0 = base[(size_t)s0 * 32 + l];
                    uint4 v1 = base[(size_t)s1 * 32 + l];
                    a0 += bflo(v0.x); a1 += bfhi(v0.x); a2 += bflo(v0.y); a3 += bfhi(v0.y);
                    a4 += bflo(v0.z); a5 += bfhi(v0.z); a6 += bflo(v0.w); a7 += bfhi(v0.w);
                    a0 += bflo(v1.x); a1 += bfhi(v1.x); a2 += bflo(v1.y); a3 += bfhi(v1.y);
                    a4 += bflo(v1.z); a5 += bfhi(v1.z); a6 += bflo(v1.w); a7 += bfhi(v1.w);
                }
                for (; i < e; ++i) {
                    uint4 v0 = base[(size_t)col[i] * 32 + l];
                    a0 += bflo(v0.x); a1 += bfhi(v0.x); a2 += bflo(v0.y); a3 += bfhi(v0.y);
                    a4 += bflo(v0.z); a5 += bfhi(v0.z); a6 += bflo(v0.w); a7 += bfhi(v0.w);
                }
            }
            short8 st;
            st[0] = (short)f2bf(a0); st[1] = (short)f2bf(a1);
            st[2] = (short)f2bf(a2); st[3] = (short)f2bf(a3);
            st[4] = (short)f2bf(a4); st[5] = (short)f2bf(a5);
            st[6] = (short)f2bf(a6); st[7] = (short)f2bf(a7);
            *(short8*)&hs[row * 264 + l * 8] = st;
        }
    }
    __syncthreads();

    const int wv = tid >> 6, l = tid & 63, q = l >> 4, m = l & 15;

    for (int br = 0; br < 2; ++br) {
        const int w1off = br ? W3T_OFF : W3S_OFF;
        const int w2off = br ? W4T_OFF : W4S_OFF;
        const float* B1 = br ? b3t : b3s;
        const float* B2 = br ? b4t : b4s;
        if (br) __syncthreads();   // br0 stage2 hm reads done before rewrite

        // ---- stage 1: hm = relu(hs[:, br*128..] @ W3 + b3), K=128 ----
        #pragma unroll
        for (int ti = 0; ti < 2; ++ti) {
            const int tile = wv * 2 + ti;
            const int ct = tile & 7;
            const int nt = tile >> 3;
            float bias = B1[ct * 16 + m];
            short8 a[4];
            #pragma unroll
            for (int kt = 0; kt < 4; ++kt)
                a[kt] = *(const short8*)&hs[(nt * 16 + m) * 264 + br * 128 + kt * 32 + q * 8];
            f32x4 acc = {0.f, 0.f, 0.f, 0.f};
            #pragma unroll
            for (int kt = 0; kt < 4; ++kt) {
                short8 bf = *(const short8*)&pack[w1off + ((size_t)(ct * 4 + kt) * 64 + l) * 8];
                acc = __builtin_amdgcn_mfma_f32_16x16x32_bf16(a[kt], bf, acc, 0, 0, 0);
            }
            #pragma unroll
            for (int r = 0; r < 4; ++r) {
                float v = fmaxf(acc[r] + bias, 0.f);
                hm[(nt * 16 + q * 4 + r) * 136 + ct * 16 + m] = f2bf(v);
            }
        }
        __syncthreads();

        // ---- stage 2: z2cat slice = hm @ W4 + b4 (8 tiles over 8 waves) ----
        {
            const int ct = wv & 3;
            const int nt = wv >> 2;
            float bias = B2[ct * 16 + m];
            short8 a[4];
            #pragma unroll
            for (int kt = 0; kt < 4; ++kt)
                a[kt] = *(const short8*)&hm[(nt * 16 + m) * 136 + kt * 32 + q * 8];
            f32x4 acc = {0.f, 0.f, 0.f, 0.f};
            #pragma unroll
            for (int kt = 0; kt < 4; ++kt) {
                short8 bf = *(const short8*)&pack[w2off + ((size_t)(ct * 4 + kt) * 64 + l) * 8];
                acc = __builtin_amdgcn_mfma_f32_16x16x32_bf16(a[kt], bf, acc, 0, 0, 0);
            }
            #pragma unroll
            for (int r = 0; r < 4; ++r) {
                int gn = n0blk + nt * 16 + q * 4 + r;
                if (gn < N)
                    z2cat[(size_t)gn * 128 + br * 64 + ct * 16 + m] = acc[r] + bias;
            }
        }
    }
}

// ---------------- per-graph 9x9 gram from z2cat [N,128] (s=0..63,t=64..127)
// 3 graphs per 256-thread block; 243 compute lanes; k-order unchanged.
__global__ __launch_bounds__(256) void einsum9_kernel(
    const float* __restrict__ z2cat, float* __restrict__ out, int G)
{
    int g0 = blockIdx.x * 3;
    __shared__ float ss[27][68];
    __shared__ float tt[27][68];
    const int tid = threadIdx.x;
    for (int idx = tid; idx < 27 * 16; idx += 256) {
        int n = idx >> 4, k4 = idx & 15;
        int g = g0 + n / 9;
        if (g < G) {
            size_t row = (size_t)(g * 9 + (n % 9)) * 128;
            float4 a = *(const float4*)&z2cat[row + k4 * 4];
            float4 b = *(const float4*)&z2cat[row + 64 + k4 * 4];
            *(float4*)&ss[n][k4 * 4] = a;
            *(float4*)&tt[n][k4 * 4] = b;
        }
    }
    __syncthreads();
    if (tid < 243) {
        int gl = tid / 81, rem = tid - gl * 81;
        int i = rem / 9, j = rem - i * 9;
        int g = g0 + gl;
        if (g < G) {
            float acc = 0.f;
            #pragma unroll
            for (int k = 0; k < 64; ++k) acc += ss[gl * 9 + i][k] * tt[gl * 9 + j][k];
            out[(size_t)g * 81 + i * 9 + j] = acc;
        }
    }
}

extern "C" void kernel_launch(void* const* d_in, const int* in_sizes, int n_in,
                              void* d_out, int out_size, void* d_ws, size_t ws_size,
                              hipStream_t stream)
{
    const float* x  = (const float*)d_in[0];
    const int*   ei = (const int*)d_in[1];
    const int N_ = in_sizes[0] / 30;
    const int E_ = in_sizes[1] / 2;
    const int* src = ei;
    const int* dst = ei + E_;

    const float* w1s = (const float*)d_in[2];
    const float* b1s = (const float*)d_in[3];
    const float* w2s = (const float*)d_in[4];
    const float* b2s = (const float*)d_in[5];
    const float* w3s = (const float*)d_in[6];
    const float* b3s = (const float*)d_in[7];
    const float* w4s = (const float*)d_in[8];
    const float* b4s = (const float*)d_in[9];
    const float* w1t = (const float*)d_in[10];
    const float* b1t = (const float*)d_in[11];
    const float* w2t = (const float*)d_in[12];
    const float* b2t = (const float*)d_in[13];
    const float* w3t = (const float*)d_in[14];
    const float* b3t = (const float*)d_in[15];
    const float* w4t = (const float*)d_in[16];
    const float* b4t = (const float*)d_in[17];

    // ---- workspace layout ----
    int* deg  = (int*)d_ws;                               // N
    int* colb = deg + N_;                                 // N * MAXDEG
    size_t int_bytes = ((size_t)N_ * (1 + MAXDEG)) * sizeof(int);
    size_t pb = (int_bytes + 15) & ~(size_t)15;
    unsigned short* packu = (unsigned short*)((char*)d_ws + pb);
    float* xpad = (float*)(packu + PACK_USHORTS);         // [N,32] fp32
    unsigned short* h1    = (unsigned short*)(xpad + (size_t)N_ * 32); // [N,32] bf16
    unsigned short* z1cat = h1 + (size_t)N_ * 32;         // [N,256] bf16 s||t
    float* z2cat = (float*)(z1cat + (size_t)N_ * 256);    // [N,128] fp32 s||t
    size_t need = pb + (size_t)PACK_USHORTS * 2
                + (size_t)N_ * 32 * 4            // xpad
                + (size_t)N_ * 32 * 2            // h1
                + (size_t)N_ * 256 * 2           // z1cat
                + (size_t)N_ * 128 * 4;          // z2cat
    if (ws_size < need) return;

    const int nbE  = (E_ + 255) / 256;
    const int nb64 = (N_ + 63) / 64;
    const int nb32 = (N_ + 31) / 32;

    // ---- prep: weight packing + x padding + deg zeroing (one kernel) ----
    prep_kernel<<<WPACK_BLOCKS + (N_ * 32 + 255) / 256, 256, 0, stream>>>(
        w1s, w2s, w3s, w4s, w1t, w2t, w3t, w4t, packu, x, xpad, deg, N_);

    // ---- adjacency: single-pass bucket scatter ----
    bucket_kernel<<<nbE, 256, 0, stream>>>(src, dst, deg, colb, E_);

    // ---- layer-1 aggregation: 8 lanes/node float4 gather -> bf16 h1 ----
    gather30_kernel<<<(N_ * 8 + 255) / 256, 256, 0, stream>>>(
        xpad, deg, colb, h1, N_);

    // ---- layer 1: both branches (MFMA), writes bf16 z1cat ----
    mlp1_kernel<<<nb64, 256, 0, stream>>>(h1, packu,
        b1s, b2s, b1t, b2t, z1cat, N_);

    // ---- layer 2: gather + both branches fused (MFMA, 512 thr / 32 nodes) ----
    mlp2_kernel<<<nb32, 512, 0, stream>>>(z1cat, deg, colb, packu,
        b3s, b4s, b3t, b4t, z2cat, N_);

    // ---- per-graph 9x9 gram: 3 graphs per block ----
    {
        int G = N_ / 9;
        einsum9_kernel<<<(G + 2) / 3, 256, 0, stream>>>(z2cat, (float*)d_out, G);
    }
}

// Round 14
// 243.027 us; speedup vs baseline: 1.1172x; 1.0050x over previous
//
#include <hip/hip_runtime.h>
#include <hip/hip_bf16.h>

// GIN x2 layers x2 branches + per-graph 9x9 gram einsum.
// Round 14: mlp1 -> branch-parallel (512 thr, waves 0-3 = s, 4-7 = t,
// per-branch hm) while KEEPING round-11's deferred-write + LDS transpose +
// 16B coalesced copy-out (round 12's regression was the 2-byte direct
// stores, not the branch parallelism). Everything else = round 13
// (244.2 us verified). Bytes written are identical -> absmax stays 14.5.

typedef __attribute__((ext_vector_type(8))) short short8;
typedef __attribute__((ext_vector_type(4))) float f32x4;

#define MAXDEG 64

__device__ inline unsigned short f2bf(float f) {
    union { float f; unsigned u; } v; v.f = f;
    unsigned r = v.u + 0x7fffu + ((v.u >> 16) & 1u);   // RNE
    return (unsigned short)(r >> 16);
}
__device__ inline float bflo(unsigned u) { return __uint_as_float(u << 16); }
__device__ inline float bfhi(unsigned u) { return __uint_as_float(u & 0xffff0000u); }
__device__ inline unsigned packbf(float a, float b) {
    return (unsigned)f2bf(a) | ((unsigned)f2bf(b) << 16);
}

// pack offsets (ushort units): [w1s][w2s][w3s][w4s][w1t][w2t][w3t][w4t]
#define W1S_OFF 0
#define W2S_OFF 4096
#define W3S_OFF 20480
#define W4S_OFF 36864
#define W1T_OFF 45056
#define W2T_OFF 49152
#define W3T_OFF 65536
#define W4T_OFF 81920
#define PACK_USHORTS 90112
#define WPACK_BLOCKS 176

// ---------------- prep: weight packing + x padding + deg zeroing (one kernel)
__global__ __launch_bounds__(256) void prep_kernel(
    const float* w0, const float* w1, const float* w2, const float* w3,
    const float* w4, const float* w5, const float* w6, const float* w7,
    unsigned short* __restrict__ pack,
    const float* __restrict__ x, float* __restrict__ xpad,
    int* __restrict__ deg, int N)
{
    if (blockIdx.x < WPACK_BLOCKS) {
        if (threadIdx.x >= 64) return;
        const int prefix[9] = {0, 8, 40, 72, 88, 96, 128, 160, 176};
        const int KTa[8] = {1, 4, 4, 4, 1, 4, 4, 4};
        const int KRa[8] = {30, 128, 128, 128, 30, 128, 128, 128};
        const int Ca[8]  = {128, 128, 128, 64, 128, 128, 128, 64};
        const int DOFF[8] = {W1S_OFF, W2S_OFF, W3S_OFF, W4S_OFF,
                             W1T_OFF, W2T_OFF, W3T_OFF, W4T_OFF};
        const float* Ws[8] = {w0, w1, w2, w3, w4, w5, w6, w7};
        int bid = blockIdx.x;
        int mi = 0;
        while (mi < 7 && bid >= prefix[mi + 1]) ++mi;
        int lt = bid - prefix[mi];
        int kt = lt % KTa[mi], ct = lt / KTa[mi];
        const float* W = Ws[mi];
        int l = threadIdx.x;
        int n = ct * 16 + (l & 15);
        for (int j = 0; j < 8; ++j) {
            int k = kt * 32 + (l >> 4) * 8 + j;
            float v = (k < KRa[mi]) ? W[(size_t)k * Ca[mi] + n] : 0.f;
            pack[(size_t)DOFF[mi] + (size_t)lt * 512 + l * 8 + j] = f2bf(v);
        }
    } else {
        int gid = (blockIdx.x - WPACK_BLOCKS) * 256 + threadIdx.x;
        if (gid < N) deg[gid] = 0;
        if (gid >= N * 32) return;
        int n = gid >> 5, f = gid & 31;
        xpad[gid] = (f < 30) ? x[(size_t)n * 30 + f] : 0.f;
    }
}

// ------------------------- adjacency build: single-pass bucket scatter
__global__ __launch_bounds__(256) void bucket_kernel(
    const int* __restrict__ src, const int* __restrict__ dst,
    int* __restrict__ deg, int* __restrict__ colb, int E)
{
    int e = blockIdx.x * 256 + threadIdx.x;
    if (e < E) {
        int d = dst[e];
        int slot = atomicAdd(&deg[d], 1);
        if (slot < MAXDEG) colb[(size_t)d * MAXDEG + slot] = src[e];
    }
}

// ------------------------------------------- layer-1 aggregation (gather)
// 8 lanes/node, float4 (16B) per lane over xpad[N,32] fp32.
__global__ __launch_bounds__(256) void gather30_kernel(
    const float* __restrict__ xpad, const int* __restrict__ deg,
    const int* __restrict__ colb, unsigned short* __restrict__ h1, int N)
{
    int gid = blockIdx.x * 256 + threadIdx.x;
    int node = gid >> 3;
    if (node >= N) return;
    int l = gid & 7;
    const float4* base = (const float4*)xpad;   // 8 float4 per row
    float4 a = base[(size_t)node * 8 + l];      // self (exact fp32)
    const int* col = colb + (size_t)node * MAXDEG;
    int e = min(deg[node], MAXDEG);
    int i = 0;
    for (; i + 4 <= e; i += 4) {
        int s0 = col[i], s1 = col[i + 1], s2 = col[i + 2], s3 = col[i + 3];
        float4 v0 = base[(size_t)s0 * 8 + l];
        float4 v1 = base[(size_t)s1 * 8 + l];
        float4 v2 = base[(size_t)s2 * 8 + l];
        float4 v3 = base[(size_t)s3 * 8 + l];
        a.x += v0.x; a.y += v0.y; a.z += v0.z; a.w += v0.w;
        a.x += v1.x; a.y += v1.y; a.z += v1.z; a.w += v1.w;
        a.x += v2.x; a.y += v2.y; a.z += v2.z; a.w += v2.w;
        a.x += v3.x; a.y += v3.y; a.z += v3.z; a.w += v3.w;
    }
    for (; i + 2 <= e; i += 2) {
        int s0 = col[i], s1 = col[i + 1];
        float4 v0 = base[(size_t)s0 * 8 + l];
        float4 v1 = base[(size_t)s1 * 8 + l];
        a.x += v0.x; a.y += v0.y; a.z += v0.z; a.w += v0.w;
        a.x += v1.x; a.y += v1.y; a.z += v1.z; a.w += v1.w;
    }
    for (; i < e; ++i) {
        float4 v0 = base[(size_t)col[i] * 8 + l];
        a.x += v0.x; a.y += v0.y; a.z += v0.z; a.w += v0.w;
    }
    uint2 o; o.x = packbf(a.x, a.y); o.y = packbf(a.z, a.w);
    ((uint2*)h1)[(size_t)node * 8 + l] = o;
}

// ------------- layer-1 MLP: branch-parallel (512 thr, 64 nodes), with
// round-11's deferred write + LDS transpose + 16B coalesced copy-out.
__global__ __launch_bounds__(512, 8) void mlp1_kernel(
    const unsigned short* __restrict__ h1, const unsigned short* __restrict__ pack,
    const float* __restrict__ b1s, const float* __restrict__ b2s,
    const float* __restrict__ b1t, const float* __restrict__ b2t,
    unsigned short* __restrict__ z1cat, int N)
{
    __shared__ __align__(16) unsigned short hs[64 * 40];        //  5.1 KB
    __shared__ __align__(16) unsigned short hm[2][64 * 136];    // 34.8 KB
    const int tid = threadIdx.x;
    const int n0blk = blockIdx.x * 64;

    // ---- stage h1 rows (32 bf16 each): 512 thr x uint2 covers 64x32 ----
    {
        int row = tid >> 3, off = tid & 7;
        int gn = n0blk + row;
        uint2 v = {0u, 0u};
        if (gn < N) v = *(const uint2*)&h1[(size_t)gn * 32 + off * 4];
        *(uint2*)&hs[row * 40 + off * 4] = v;
    }
    __syncthreads();

    const int half = tid >> 8;         // 0 = branch s, 1 = branch t
    const int ltid = tid & 255;
    const int wv = ltid >> 6, l = ltid & 63, q = l >> 4, m = l & 15;
    const float* B1 = half ? b1t : b1s;
    const float* B2 = half ? b2t : b2s;
    const int w1off = half ? W1T_OFF : W1S_OFF;
    const int w2off = half ? W2T_OFF : W2S_OFF;
    unsigned short* hmb = hm[half];

    // ---- stage 1: hm = relu(h1 @ W1 + b1), K=32 single MFMA ----
    {
        short8 a[4];
        #pragma unroll
        for (int nt = 0; nt < 4; ++nt)
            a[nt] = *(const short8*)&hs[(nt * 16 + m) * 40 + q * 8];
        #pragma unroll
        for (int ci = 0; ci < 2; ++ci) {
            int ct = wv * 2 + ci;
            short8 bf = *(const short8*)&pack[w1off + ((size_t)ct * 64 + l) * 8];
            float bias = B1[ct * 16 + m];
            #pragma unroll
            for (int nt = 0; nt < 4; ++nt) {
                f32x4 acc = {0.f, 0.f, 0.f, 0.f};
                acc = __builtin_amdgcn_mfma_f32_16x16x32_bf16(a[nt], bf, acc, 0, 0, 0);
                #pragma unroll
                for (int r = 0; r < 4; ++r) {
                    float v = fmaxf(acc[r] + bias, 0.f);
                    hmb[(nt * 16 + q * 4 + r) * 136 + ct * 16 + m] = f2bf(v);
                }
            }
        }
    }
    __syncthreads();

    // ---- stage 2: acc2 = hm @ W2 (K=128), deferred write ----
    f32x4 acc2[4][2];
    #pragma unroll
    for (int nt = 0; nt < 4; ++nt)
        #pragma unroll
        for (int ci = 0; ci < 2; ++ci)
            acc2[nt][ci] = (f32x4){0.f, 0.f, 0.f, 0.f};
    for (int nt = 0; nt < 4; ++nt) {
        short8 a[4];
        #pragma unroll
        for (int kt = 0; kt < 4; ++kt)
            a[kt] = *(const short8*)&hmb[(nt * 16 + m) * 136 + kt * 32 + q * 8];
        #pragma unroll
        for (int ci = 0; ci < 2; ++ci) {
            int ct = wv * 2 + ci;
            #pragma unroll
            for (int kt = 0; kt < 4; ++kt) {
                short8 bf = *(const short8*)&pack[w2off + ((size_t)(ct * 4 + kt) * 64 + l) * 8];
                acc2[nt][ci] = __builtin_amdgcn_mfma_f32_16x16x32_bf16(a[kt], bf, acc2[nt][ci], 0, 0, 0);
            }
        }
    }
    __syncthreads();   // all hm A-frag reads complete
    #pragma unroll
    for (int ci = 0; ci < 2; ++ci) {
        int ct = wv * 2 + ci;
        float bias = B2[ct * 16 + m];
        #pragma unroll
        for (int nt = 0; nt < 4; ++nt)
            #pragma unroll
            for (int r = 0; r < 4; ++r)
                hmb[(nt * 16 + q * 4 + r) * 136 + ct * 16 + m] =
                    f2bf(acc2[nt][ci][r] + bias);
    }
    __syncthreads();
    // combined coalesced copy-out: 64 rows x 256 bf16 (s cols 0..127 from
    // hm[0], t cols 128..255 from hm[1]); 2048 16B chunks over 512 threads.
    for (int c = tid; c < 2048; c += 512) {
        int row = c >> 5, off = c & 31;
        int gn = n0blk + row;
        if (gn < N) {
            short8 v = *(const short8*)&hm[off >> 4][row * 136 + (off & 15) * 8];
            *(short8*)&z1cat[(size_t)gn * 256 + off * 8] = v;
        }
    }
}

// ---------------- layer-2: gather + both-branch MLP fused (512 thr, 32 nodes)
// At its measured floor (~75 us across 4 structural variants).
__global__ __launch_bounds__(512, 8) void mlp2_kernel(
    const unsigned short* __restrict__ z1, const int* __restrict__ deg,
    const int* __restrict__ colb, const unsigned short* __restrict__ pack,
    const float* __restrict__ b3s, const float* __restrict__ b4s,
    const float* __restrict__ b3t, const float* __restrict__ b4t,
    float* __restrict__ z2cat, int N)
{
    __shared__ __align__(16) unsigned short hs[32 * 264];
    __shared__ __align__(16) unsigned short hm[32 * 136];
    const int tid = threadIdx.x;
    const int n0blk = blockIdx.x * 32;

    // ---- gather-stage: 16 groups x 32 lanes, 2 rows per group ----
    {
        const int g = tid >> 5, l = tid & 31;
        const uint4* base = (const uint4*)z1;        // 32 uint4 per row
        for (int it = 0; it < 2; ++it) {
            int row = it * 16 + g;
            int gn = n0blk + row;
            float a0 = 0.f, a1 = 0.f, a2 = 0.f, a3 = 0.f;
            float a4 = 0.f, a5 = 0.f, a6 = 0.f, a7 = 0.f;
            if (gn < N) {
                uint4 s = base[(size_t)gn * 32 + l];     // self
                a0 = bflo(s.x); a1 = bfhi(s.x); a2 = bflo(s.y); a3 = bfhi(s.y);
                a4 = bflo(s.z); a5 = bfhi(s.z); a6 = bflo(s.w); a7 = bfhi(s.w);
                const int* col = colb + (size_t)gn * MAXDEG;
                int e = min(deg[gn], MAXDEG);
                int i = 0;
                for (; i + 4 <= e; i += 4) {
                    int s0 = col[i], s1 = col[i + 1], s2 = col[i + 2], s3 = col[i + 3];
                    uint4 v0 = base[(size_t)s0 * 32 + l];
                    uint4 v1 = base[(size_t)s1 * 32 + l];
                    uint4 v2 = base[(size_t)s2 * 32 + l];
                    uint4 v3 = base[(size_t)s3 * 32 + l];
                    a0 += bflo(v0.x); a1 += bfhi(v0.x); a2 += bflo(v0.y); a3 += bfhi(v0.y);
                    a4 += bflo(v0.z); a5 += bfhi(v0.z); a6 += bflo(v0.w); a7 += bfhi(v0.w);
                    a0 += bflo(v1.x); a1 += bfhi(v1.x); a2 += bflo(v1.y); a3 += bfhi(v1.y);
                    a4 += bflo(v1.z); a5 += bfhi(v1.z); a6 += bflo(v1.w); a7 += bfhi(v1.w);
                    a0 += bflo(v2.x); a1 += bfhi(v2.x); a2 += bflo(v2.y); a3 += bfhi(v2.y);
                    a4 += bflo(v2.z); a5 += bfhi(v2.z); a6 += bflo(v2.w); a7 += bfhi(v2.w);
                    a0 += bflo(v3.x); a1 += bfhi(v3.x); a2 += bflo(v3.y); a3 += bfhi(v3.y);
                    a4 += bflo(v3.z); a5 += bfhi(v3.z); a6 += bflo(v3.w); a7 += bfhi(v3.w);
                }
                for (; i + 2 <= e; i += 2) {
                    int s0 = col[i], s1 = col[i + 1];
                    uint4 v0 = base[(size_t)s0 * 32 + l];
                    uint4 v1 = base[(size_t)s1 * 32 + l];
                    a0 += bflo(v0.x); a1 += bfhi(v0.x); a2 += bflo(v0.y); a3 += bfhi(v0.y);
                    a4 += bflo(v0.z); a5 += bfhi(v0.z); a6 += bflo(v0.w); a7 += bfhi(v0.w);
                    a0 += bflo(v1.x); a1 += bfhi(v1.x); a2 += bflo(v1.y); a3 += bfhi(v1.y);
                    a4 += bflo(v1.z); a5 += bfhi(v1.z); a6 += bflo(v1.w); a7 += bfhi(v1.w);
                }
                for (; i < e; ++i) {
                    uint4 v0 = base[(size_t)col[i] * 32 + l];
                    a0 += bflo(v0.x); a1 += bfhi(v0.x); a2 += bflo(v0.y); a3 += bfhi(v0.y);
                    a4 += bflo(v0.z); a5 += bfhi(v0.z); a6 += bflo(v0.w); a7 += bfhi(v0.w);
                }
            }
            short8 st;
            st[0] = (short)f2bf(a0); st[1] = (short)f2bf(a1);
            st[2] = (short)f2bf(a2); st[3] = (short)f2bf(a3);
            st[4] = (short)f2bf(a4); st[5] = (short)f2bf(a5);
            st[6] = (short)f2bf(a6); st[7] = (short)f2bf(a7);
            *(short8*)&hs[row * 264 + l * 8] = st;
        }
    }
    __syncthreads();

    const int wv = tid >> 6, l = tid & 63, q = l >> 4, m = l & 15;

    for (int br = 0; br < 2; ++br) {
        const int w1off = br ? W3T_OFF : W3S_OFF;
        const int w2off = br ? W4T_OFF : W4S_OFF;
        const float* B1 = br ? b3t : b3s;
        const float* B2 = br ? b4t : b4s;
        if (br) __syncthreads();   // br0 stage2 hm reads done before rewrite

        // ---- stage 1: hm = relu(hs[:, br*128..] @ W3 + b3), K=128 ----
        #pragma unroll
        for (int ti = 0; ti < 2; ++ti) {
            const int tile = wv * 2 + ti;
            const int ct = tile & 7;
            const int nt = tile >> 3;
            float bias = B1[ct * 16 + m];
            short8 a[4];
            #pragma unroll
            for (int kt = 0; kt < 4; ++kt)
                a[kt] = *(const short8*)&hs[(nt * 16 + m) * 264 + br * 128 + kt * 32 + q * 8];
            f32x4 acc = {0.f, 0.f, 0.f, 0.f};
            #pragma unroll
            for (int kt = 0; kt < 4; ++kt) {
                short8 bf = *(const short8*)&pack[w1off + ((size_t)(ct * 4 + kt) * 64 + l) * 8];
                acc = __builtin_amdgcn_mfma_f32_16x16x32_bf16(a[kt], bf, acc, 0, 0, 0);
            }
            #pragma unroll
            for (int r = 0; r < 4; ++r) {
                float v = fmaxf(acc[r] + bias, 0.f);
                hm[(nt * 16 + q * 4 + r) * 136 + ct * 16 + m] = f2bf(v);
            }
        }
        __syncthreads();

        // ---- stage 2: z2cat slice = hm @ W4 + b4 (8 tiles over 8 waves) ----
        {
            const int ct = wv & 3;
            const int nt = wv >> 2;
            float bias = B2[ct * 16 + m];
            short8 a[4];
            #pragma unroll
            for (int kt = 0; kt < 4; ++kt)
                a[kt] = *(const short8*)&hm[(nt * 16 + m) * 136 + kt * 32 + q * 8];
            f32x4 acc = {0.f, 0.f, 0.f, 0.f};
            #pragma unroll
            for (int kt = 0; kt < 4; ++kt) {
                short8 bf = *(const short8*)&pack[w2off + ((size_t)(ct * 4 + kt) * 64 + l) * 8];
                acc = __builtin_amdgcn_mfma_f32_16x16x32_bf16(a[kt], bf, acc, 0, 0, 0);
            }
            #pragma unroll
            for (int r = 0; r < 4; ++r) {
                int gn = n0blk + nt * 16 + q * 4 + r;
                if (gn < N)
                    z2cat[(size_t)gn * 128 + br * 64 + ct * 16 + m] = acc[r] + bias;
            }
        }
    }
}

// ---------------- per-graph 9x9 gram from z2cat [N,128] (s=0..63,t=64..127)
// 3 graphs per 256-thread block; 243 compute lanes; k-order unchanged.
__global__ __launch_bounds__(256) void einsum9_kernel(
    const float* __restrict__ z2cat, float* __restrict__ out, int G)
{
    int g0 = blockIdx.x * 3;
    __shared__ float ss[27][68];
    __shared__ float tt[27][68];
    const int tid = threadIdx.x;
    for (int idx = tid; idx < 27 * 16; idx += 256) {
        int n = idx >> 4, k4 = idx & 15;
        int g = g0 + n / 9;
        if (g < G) {
            size_t row = (size_t)(g * 9 + (n % 9)) * 128;
            float4 a = *(const float4*)&z2cat[row + k4 * 4];
            float4 b = *(const float4*)&z2cat[row + 64 + k4 * 4];
            *(float4*)&ss[n][k4 * 4] = a;
            *(float4*)&tt[n][k4 * 4] = b;
        }
    }
    __syncthreads();
    if (tid < 243) {
        int gl = tid / 81, rem = tid - gl * 81;
        int i = rem / 9, j = rem - i * 9;
        int g = g0 + gl;
        if (g < G) {
            float acc = 0.f;
            #pragma unroll
            for (int k = 0; k < 64; ++k) acc += ss[gl * 9 + i][k] * tt[gl * 9 + j][k];
            out[(size_t)g * 81 + i * 9 + j] = acc;
        }
    }
}

extern "C" void kernel_launch(void* const* d_in, const int* in_sizes, int n_in,
                              void* d_out, int out_size, void* d_ws, size_t ws_size,
                              hipStream_t stream)
{
    const float* x  = (const float*)d_in[0];
    const int*   ei = (const int*)d_in[1];
    const int N_ = in_sizes[0] / 30;
    const int E_ = in_sizes[1] / 2;
    const int* src = ei;
    const int* dst = ei + E_;

    const float* w1s = (const float*)d_in[2];
    const float* b1s = (const float*)d_in[3];
    const float* w2s = (const float*)d_in[4];
    const float* b2s = (const float*)d_in[5];
    const float* w3s = (const float*)d_in[6];
    const float* b3s = (const float*)d_in[7];
    const float* w4s = (const float*)d_in[8];
    const float* b4s = (const float*)d_in[9];
    const float* w1t = (const float*)d_in[10];
    const float* b1t = (const float*)d_in[11];
    const float* w2t = (const float*)d_in[12];
    const float* b2t = (const float*)d_in[13];
    const float* w3t = (const float*)d_in[14];
    const float* b3t = (const float*)d_in[15];
    const float* w4t = (const float*)d_in[16];
    const float* b4t = (const float*)d_in[17];

    // ---- workspace layout ----
    int* deg  = (int*)d_ws;                               // N
    int* colb = deg + N_;                                 // N * MAXDEG
    size_t int_bytes = ((size_t)N_ * (1 + MAXDEG)) * sizeof(int);
    size_t pb = (int_bytes + 15) & ~(size_t)15;
    unsigned short* packu = (unsigned short*)((char*)d_ws + pb);
    float* xpad = (float*)(packu + PACK_USHORTS);         // [N,32] fp32
    unsigned short* h1    = (unsigned short*)(xpad + (size_t)N_ * 32); // [N,32] bf16
    unsigned short* z1cat = h1 + (size_t)N_ * 32;         // [N,256] bf16 s||t
    float* z2cat = (float*)(z1cat + (size_t)N_ * 256);    // [N,128] fp32 s||t
    size_t need = pb + (size_t)PACK_USHORTS * 2
                + (size_t)N_ * 32 * 4            // xpad
                + (size_t)N_ * 32 * 2            // h1
                + (size_t)N_ * 256 * 2           // z1cat
                + (size_t)N_ * 128 * 4;          // z2cat
    if (ws_size < need) return;

    const int nbE  = (E_ + 255) / 256;
    const int nb64 = (N_ + 63) / 64;
    const int nb32 = (N_ + 31) / 32;

    // ---- prep: weight packing + x padding + deg zeroing (one kernel) ----
    prep_kernel<<<WPACK_BLOCKS + (N_ * 32 + 255) / 256, 256, 0, stream>>>(
        w1s, w2s, w3s, w4s, w1t, w2t, w3t, w4t, packu, x, xpad, deg, N_);

    // ---- adjacency: single-pass bucket scatter ----
    bucket_kernel<<<nbE, 256, 0, stream>>>(src, dst, deg, colb, E_);

    // ---- layer-1 aggregation: 8 lanes/node float4 gather -> bf16 h1 ----
    gather30_kernel<<<(N_ * 8 + 255) / 256, 256, 0, stream>>>(
        xpad, deg, colb, h1, N_);

    // ---- layer 1: both branches in parallel (MFMA, 512 thr / 64 nodes) ----
    mlp1_kernel<<<nb64, 512, 0, stream>>>(h1, packu,
        b1s, b2s, b1t, b2t, z1cat, N_);

    // ---- layer 2: gather + both branches fused (MFMA, 512 thr / 32 nodes) ----
    mlp2_kernel<<<nb32, 512, 0, stream>>>(z1cat, deg, colb, packu,
        b3s, b4s, b3t, b4t, z2cat, N_);

    // ---- per-graph 9x9 gram: 3 graphs per block ----
    {
        int G = N_ / 9;
        einsum9_kernel<<<(G + 2) / 3, 256, 0, stream>>>(z2cat, (float*)d_out, G);
    }
}